// Round 6
// baseline (219.403 us; speedup 1.0000x reference)
//
#include <hip/hip_runtime.h>

// Spherical: out = x * |s|  (x: 8192x4096 fp32, s: scalar fp32)
// Pure streaming scale — memory-bound, zero reuse.
//
// R6: complete the cache-hint 2x2 (structure frozen: depth=1, flat
// exact-cover, 32768 blk x 256 thr):
//   nt    / nt      ~57-59 us  (R0/R4)
//   nt    / plain   ~58 us     (R5 — store hint free)
//   plain / nt      ~85 us     (R2)
//   plain / plain   THIS ROUND
// Theory: R2's plain-load penalty may be an INTERACTION with nt stores
// (read-allocate churn serializing against an L2-bypassing store
// stream). plain/plain is the standard memcpy regime — the very regime
// the 6.29 TB/s float4-copy ubench and the 6.7 TB/s harness fill run
// in, with stores retiring into L2 and written back lazily.
// Discriminates: fast -> interaction (adopt); slow -> plain loads
// intrinsically bad, nt/nt is the ceiling (revert + declare).

typedef float fvec4 __attribute__((ext_vector_type(4)));

__global__ __launch_bounds__(256) void spherical_scale_kernel(
    const fvec4* __restrict__ x4,
    const float* __restrict__ s_ptr,
    fvec4* __restrict__ out4,
    int n4)   // number of fvec4 elements
{
    const float s = fabsf(s_ptr[0]);
    const int i = blockIdx.x * blockDim.x + threadIdx.x;

    if (i < n4) {
        fvec4 a = x4[i];   // PLAIN load
        a *= s;
        out4[i] = a;       // PLAIN store
    }
}

extern "C" void kernel_launch(void* const* d_in, const int* in_sizes, int n_in,
                              void* d_out, int out_size, void* d_ws, size_t ws_size,
                              hipStream_t stream) {
    const float* x = (const float*)d_in[0];
    const float* s = (const float*)d_in[1];
    float* out = (float*)d_out;

    const int n = in_sizes[0];        // 8192*4096 = 33554432 floats
    const int n4 = n / 4;             // 8388608 fvec4s
    const int block = 256;
    const int grid = (n4 + block - 1) / block;   // 32768 blocks, 1 fvec4/thread

    spherical_scale_kernel<<<grid, block, 0, stream>>>(
        (const fvec4*)x, s, (fvec4*)out, n4);
}